// Round 16
// baseline (99.568 us; speedup 1.0000x reference)
//
#include <hip/hip_runtime.h>
#include <hip/hip_bf16.h>

#define N_NODES 100000
#define N_EDGES 1600000
#define DIM 64
#define NBUCK 782        // ceil(N_NODES / 128), bucket = col >> 7
#define BK_NODES 128
#define CAP 2560         // slots per bucket (mean 2048, sigma ~45 -> >11 sigma)
#define HA_EPB 16384     // edges per block in scatter (98 blocks; r6-proven)
#define HA_BLOCKS 98
#define GEMM_BLOCKS 391  // ceil(N_NODES / 256), 16 waves x 16 nodes each

typedef unsigned int uint32;
typedef __attribute__((ext_vector_type(8))) short bf16x8;
typedef __attribute__((ext_vector_type(4))) float f32x4;

// bf16 (u16 pair packed in u32) -> float helpers
__device__ __forceinline__ float bflo(uint32 u) { return __uint_as_float(u << 16); }
__device__ __forceinline__ float bfhi(uint32 u) { return __uint_as_float(u & 0xffff0000u); }

__device__ __forceinline__ short f2bf(float f) {
    __hip_bfloat16 h = __float2bfloat16(f);
    return (short)__builtin_bit_cast(unsigned short, h);
}
__device__ __forceinline__ uint32 pack2bf(float lo, float hi) {
    unsigned short a = __builtin_bit_cast(unsigned short, __float2bfloat16(lo));
    unsigned short b = __builtin_bit_cast(unsigned short, __float2bfloat16(hi));
    return ((uint32)b << 16) | (uint32)a;
}

// ---------------------------------------------------------------------------
// 0) init: zero bucket counters AND pre-convert W to bf16 (once).
// ---------------------------------------------------------------------------
__global__ __launch_bounds__(1024) void init_kernel(const float* __restrict__ W,
                                                    unsigned short* __restrict__ Wbf,
                                                    int* __restrict__ bcnt) {
    int i = blockIdx.x * 1024 + threadIdx.x;
    if (i < DIM * DIM)
        Wbf[i] = __builtin_bit_cast(unsigned short, __float2bfloat16(W[i]));
    if (blockIdx.x == 0 && threadIdx.x < NBUCK) bcnt[threadIdx.x] = 0;
}

// ---------------------------------------------------------------------------
// 1) FUSED scatter || gemm (one dispatch; gemm blocks fill CUs scatter
//    leaves idle). Read-once streams (x, row, col) use non-temporal loads
//    so they don't evict L2 lines needed by pairs writes / later sb reads.
//    blocks 0..97   : r6-proven bucket scatter
//    blocks 98..488 : MFMA GEMM, UNSCALED sb = bf16(x @ W^T), swapped-operand
//                     mfma -> lane-local node rows -> direct packed stores.
// ---------------------------------------------------------------------------
__global__ __launch_bounds__(1024) void scattergemm_kernel(
        const int* __restrict__ row, const int* __restrict__ col,
        int* __restrict__ bcnt, int* __restrict__ pairs,
        const float* __restrict__ x, const unsigned short* __restrict__ Wbf,
        uint32* __restrict__ sbw) {
    __shared__ int h[NBUCK];
    __shared__ int base[NBUCK];
    const int tid = threadIdx.x;

    if (blockIdx.x < HA_BLOCKS) {
        // ---------------- scatter role (r6 exact + NT edge loads) ----------
        if (tid < NBUCK) h[tid] = 0;
        __syncthreads();
        const int bstart = blockIdx.x * HA_EPB;
        int r[16], c[16];
#pragma unroll 16
        for (int k = 0; k < 16; ++k) {
            int e = bstart + tid + k * 1024;
            if (e < N_EDGES) {
                r[k] = __builtin_nontemporal_load(&row[e]);
                c[k] = __builtin_nontemporal_load(&col[e]);
                atomicAdd(&h[c[k] >> 7], 1);
            }
        }
        __syncthreads();
        if (tid < NBUCK) {
            int v = h[tid];
            base[tid] = v ? atomicAdd(&bcnt[tid], v) : 0;
            h[tid] = 0;  // reuse as local cursor
        }
        __syncthreads();
#pragma unroll 16
        for (int k = 0; k < 16; ++k) {
            int e = bstart + tid + k * 1024;
            if (e < N_EDGES) {
                int bk = c[k] >> 7;
                int pos = base[bk] + atomicAdd(&h[bk], 1);
                if (pos < CAP) pairs[bk * CAP + pos] = (r[k] << 7) | (c[k] & 127);
            }
        }
    } else {
        // ---------------- gemm role ----------------
        const int w = tid >> 6;
        const int lane = tid & 63;
        const int r16 = lane & 15;   // node within 16-row tile
        const int kb = lane >> 4;    // k-block / feature sub-block
        const int nbase = (blockIdx.x - HA_BLOCKS) * 256 + w * 16;

        // W fragments: direct 16B bf16 loads (8KB table, cache-resident)
        bf16x8 wb[4][2];
#pragma unroll
        for (int t = 0; t < 4; ++t) {
#pragma unroll
            for (int hh = 0; hh < 2; ++hh) {
                wb[t][hh] = *(const bf16x8*)&Wbf[(r16 + 16 * t) * DIM + 32 * hh + kb * 8];
            }
        }

        int arow = nbase + r16;
        if (arow >= N_NODES) arow = N_NODES - 1;
        bf16x8 af[2];
#pragma unroll
        for (int hh = 0; hh < 2; ++hh) {
            const f32x4* xp = (const f32x4*)&x[(size_t)arow * DIM + 32 * hh + kb * 8];
            f32x4 p0 = __builtin_nontemporal_load(xp);       // x is read-once
            f32x4 p1 = __builtin_nontemporal_load(xp + 1);
            bf16x8 f;
            f[0] = f2bf(p0[0]); f[1] = f2bf(p0[1]); f[2] = f2bf(p0[2]); f[3] = f2bf(p0[3]);
            f[4] = f2bf(p1[0]); f[5] = f2bf(p1[1]); f[6] = f2bf(p1[2]); f[7] = f2bf(p1[3]);
            af[hh] = f;
        }

        const int node = nbase + r16;
        const bool valid = node < N_NODES;
#pragma unroll
        for (int t = 0; t < 4; ++t) {
            // SWAPPED operands: D[row=j, col=node] -> lane (l&15)=node owns
            // 4 consecutive feature cols j = t*16 + kb*4 + i
            f32x4 c = {0.0f, 0.0f, 0.0f, 0.0f};
            c = __builtin_amdgcn_mfma_f32_16x16x32_bf16(wb[t][0], af[0], c, 0, 0, 0);
            c = __builtin_amdgcn_mfma_f32_16x16x32_bf16(wb[t][1], af[1], c, 0, 0, 0);
            if (valid) {
                uint2 ov;
                ov.x = pack2bf(c[0], c[1]);
                ov.y = pack2bf(c[2], c[3]);
                *(uint2*)&sbw[(size_t)node * 32 + t * 8 + kb * 2] = ov;
            }
        }
    }
}

// ---------------------------------------------------------------------------
// 2) per-bucket in-place sort (512 threads: 4 serial iters/pass vs 8):
//    LDS staging, shfl wave-scan, emits info[n] = (start<<8)|deg and dinv[n].
// ---------------------------------------------------------------------------
__global__ __launch_bounds__(512) void sort_kernel(const int* __restrict__ bcnt,
                                                   int* __restrict__ pairs,
                                                   int* __restrict__ info,
                                                   float* __restrict__ dinv) {
    __shared__ int cnt[BK_NODES];
    __shared__ int sc[BK_NODES];
    __shared__ int cur[BK_NODES];
    __shared__ int buf[CAP];
    const int b = blockIdx.x;
    const int tid = threadIdx.x;
    int n = bcnt[b];
    if (n > CAP) n = CAP;
    if (tid < BK_NODES) cnt[tid] = 0;
    __syncthreads();
    for (int p = tid; p < n; p += 512) {
        int pk = __builtin_nontemporal_load(&pairs[b * CAP + p]);  // read-once
        buf[p] = pk;
        atomicAdd(&cnt[pk & 127], 1);
    }
    __syncthreads();
    // inclusive scan of cnt[0..127]: per-wave shfl scan + cross-wave fixup
    if (tid < BK_NODES) {
        int lane = tid & 63;
        int sum = cnt[tid];
#pragma unroll
        for (int d = 1; d < 64; d <<= 1) {
            int t = __shfl_up(sum, d);
            if (lane >= d) sum += t;
        }
        sc[tid] = sum;
    }
    __syncthreads();
    if (tid >= 64 && tid < BK_NODES) sc[tid] += sc[63];
    __syncthreads();
    if (tid < BK_NODES) {
        int ex = sc[tid] - cnt[tid];  // exclusive
        cur[tid] = ex;
        int node = b * BK_NODES + tid;
        if (node < N_NODES) {
            info[node] = ((b * CAP + ex) << 8) | cnt[tid];
            dinv[node] = rsqrtf((float)(cnt[tid] + 1));  // +1 self-loop
        }
    }
    __syncthreads();
    for (int p = tid; p < n; p += 512) {
        int pk = buf[p];
        int pos = atomicAdd(&cur[pk & 127], 1);
        pairs[b * CAP + pos] = pk >> 7;  // sorted source row index
    }
}

// ---------------------------------------------------------------------------
// 3) aggregate + finalize (r5 8-deep loop + per-edge dinv[r]):
//    one node per wave, uint2 x 16 lanes per 128B row, 4 quadrants,
//    unroll 2 -> 8 gathers in flight; dinv loads are L2-resident broadcast.
// ---------------------------------------------------------------------------
__global__ __launch_bounds__(256) void agg_kernel(const int* __restrict__ info,
                                                  const int* __restrict__ srow,
                                                  const uint2* __restrict__ s4,
                                                  const float* __restrict__ dinv,
                                                  const float* __restrict__ bias,
                                                  float* __restrict__ out) {
    int n = __builtin_amdgcn_readfirstlane(blockIdx.x * 4 + (threadIdx.x >> 6));
    if (n >= N_NODES) return;
    const int lane = threadIdx.x & 63;
    const int q = lane >> 4;   // quadrant 0..3: which edge in the group of 4
    const int l = lane & 15;   // 16 lanes x 8B cover one 128B row

    const int iv = info[n];
    const int start = iv >> 8;
    const int end = start + (iv & 255);

    float a0 = 0.0f, a1 = 0.0f, a2 = 0.0f, a3 = 0.0f;
    int p = start + q;
    for (; p + 4 < end; p += 8) {
        int r0 = srow[p];
        int r1 = srow[p + 4];
        float d0 = dinv[r0];
        float d1 = dinv[r1];
        uint2 u0 = s4[(size_t)r0 * 16 + l];
        uint2 u1 = s4[(size_t)r1 * 16 + l];
        a0 = fmaf(d0, bflo(u0.x), a0); a1 = fmaf(d0, bfhi(u0.x), a1);
        a2 = fmaf(d0, bflo(u0.y), a2); a3 = fmaf(d0, bfhi(u0.y), a3);
        a0 = fmaf(d1, bflo(u1.x), a0); a1 = fmaf(d1, bfhi(u1.x), a1);
        a2 = fmaf(d1, bflo(u1.y), a2); a3 = fmaf(d1, bfhi(u1.y), a3);
    }
    if (p < end) {
        int r0 = srow[p];
        float d0 = dinv[r0];
        uint2 u0 = s4[(size_t)r0 * 16 + l];
        a0 = fmaf(d0, bflo(u0.x), a0); a1 = fmaf(d0, bfhi(u0.x), a1);
        a2 = fmaf(d0, bflo(u0.y), a2); a3 = fmaf(d0, bfhi(u0.y), a3);
    }

    // merge quadrants: lanes 0-15 end up with the full sums
    a0 += __shfl_xor(a0, 16); a1 += __shfl_xor(a1, 16);
    a2 += __shfl_xor(a2, 16); a3 += __shfl_xor(a3, 16);
    a0 += __shfl_xor(a0, 32); a1 += __shfl_xor(a1, 32);
    a2 += __shfl_xor(a2, 32); a3 += __shfl_xor(a3, 32);

    if (lane < 16) {
        float dc = dinv[n];
        uint2 us = s4[(size_t)n * 16 + l];  // self-loop term (unscaled sb)
        a0 = fmaf(dc, bflo(us.x), a0); a1 = fmaf(dc, bfhi(us.x), a1);
        a2 = fmaf(dc, bflo(us.y), a2); a3 = fmaf(dc, bfhi(us.y), a3);
        float4 bb = *(const float4*)&bias[4 * l];
        f32x4 o;
        o[0] = fmaxf(fmaf(dc, a0, bb.x), 0.0f);
        o[1] = fmaxf(fmaf(dc, a1, bb.y), 0.0f);
        o[2] = fmaxf(fmaf(dc, a2, bb.z), 0.0f);
        o[3] = fmaxf(fmaf(dc, a3, bb.w), 0.0f);
        // non-temporal: out is write-once, keep it out of L2
        __builtin_nontemporal_store(o, (f32x4*)&out[(size_t)n * DIM + 4 * l]);
    }
}

extern "C" void kernel_launch(void* const* d_in, const int* in_sizes, int n_in,
                              void* d_out, int out_size, void* d_ws, size_t ws_size,
                              hipStream_t stream) {
    const float* x    = (const float*)d_in[0];
    const int*   ei   = (const int*)d_in[1];  // [2, E] int32
    const float* W    = (const float*)d_in[2];
    const float* bias = (const float*)d_in[3];
    float*       out  = (float*)d_out;

    const int* row = ei;            // source nodes
    const int* col = ei + N_EDGES;  // target nodes

    // workspace layout (bytes, 128-aligned):
    //   bcnt  int[1024]              @ 0         (4096)
    //   Wbf   ushort[4096]           @ 4096      (8192)
    //   info  int[100000]            @ 12288     (400000)
    //   dinv  float[100000]          @ 412288    (400000)
    //   pairs int[NBUCK*CAP=2001920] @ 812288    (8007680)  (reused as srow)
    //   sb    bf16[6400000]          @ 8819968   (12800000) -> end ~21.6 MB
    char* ws = (char*)d_ws;
    int*            bcnt  = (int*)(ws + 0);
    unsigned short* Wbf   = (unsigned short*)(ws + 4096);
    int*            info  = (int*)(ws + 12288);
    float*          dinv  = (float*)(ws + 412288);
    int*            pairs = (int*)(ws + 812288);
    uint32*         sbw   = (uint32*)(ws + 8819968);

    init_kernel<<<4, 1024, 0, stream>>>(W, Wbf, bcnt);
    scattergemm_kernel<<<HA_BLOCKS + GEMM_BLOCKS, 1024, 0, stream>>>(
        row, col, bcnt, pairs, x, Wbf, sbw);
    sort_kernel<<<NBUCK, 512, 0, stream>>>(bcnt, pairs, info, dinv);
    agg_kernel<<<(N_NODES + 3) / 4, 256, 0, stream>>>(info, pairs, (const uint2*)sbw,
                                                      dinv, bias, out);
}

// Round 17
// 93.433 us; speedup vs baseline: 1.0657x; 1.0657x over previous
//
#include <hip/hip_runtime.h>
#include <hip/hip_bf16.h>

#define N_NODES 100000
#define N_EDGES 1600000
#define DIM 64
#define NBUCK 782        // ceil(N_NODES / 128), bucket = col >> 7
#define BK_NODES 128
#define CAP 2560         // slots per bucket (mean 2048, sigma ~45 -> >11 sigma)
#define HA_EPB 16384     // edges per block in scatter (98 blocks; r6-proven)
#define HA_BLOCKS 98
#define GEMM_BLOCKS 391  // ceil(N_NODES / 256), 16 waves x 16 nodes each

typedef unsigned int uint32;
typedef __attribute__((ext_vector_type(8))) short bf16x8;
typedef __attribute__((ext_vector_type(4))) float f32x4;

// bf16 (u16 pair packed in u32) -> float helpers
__device__ __forceinline__ float bflo(uint32 u) { return __uint_as_float(u << 16); }
__device__ __forceinline__ float bfhi(uint32 u) { return __uint_as_float(u & 0xffff0000u); }

__device__ __forceinline__ short f2bf(float f) {
    __hip_bfloat16 h = __float2bfloat16(f);
    return (short)__builtin_bit_cast(unsigned short, h);
}
__device__ __forceinline__ uint32 pack2bf(float lo, float hi) {
    unsigned short a = __builtin_bit_cast(unsigned short, __float2bfloat16(lo));
    unsigned short b = __builtin_bit_cast(unsigned short, __float2bfloat16(hi));
    return ((uint32)b << 16) | (uint32)a;
}

// ---------------------------------------------------------------------------
// 0) init: zero bucket counters AND pre-convert W to bf16 (once).
// ---------------------------------------------------------------------------
__global__ __launch_bounds__(1024) void init_kernel(const float* __restrict__ W,
                                                    unsigned short* __restrict__ Wbf,
                                                    int* __restrict__ bcnt) {
    int i = blockIdx.x * 1024 + threadIdx.x;
    if (i < DIM * DIM)
        Wbf[i] = __builtin_bit_cast(unsigned short, __float2bfloat16(W[i]));
    if (blockIdx.x == 0 && threadIdx.x < NBUCK) bcnt[threadIdx.x] = 0;
}

// ---------------------------------------------------------------------------
// 1) FUSED scatter || gemm (one dispatch so gemm blocks fill the CUs that
//    scatter's 98 blocks leave idle).
//    blocks 0..97   : r6-proven bucket scatter
//    blocks 98..488 : MFMA GEMM, UNSCALED sb[n][j] = bf16(sum_k x[n][k]W[j][k])
//                     swapped-operand mfma -> lane-local node rows -> direct
//                     packed stores, NO LDS stage / barrier / bank conflicts.
// ---------------------------------------------------------------------------
__global__ __launch_bounds__(1024) void scattergemm_kernel(
        const int* __restrict__ row, const int* __restrict__ col,
        int* __restrict__ bcnt, int* __restrict__ pairs,
        const float* __restrict__ x, const unsigned short* __restrict__ Wbf,
        uint32* __restrict__ sbw) {
    __shared__ int h[NBUCK];
    __shared__ int base[NBUCK];
    const int tid = threadIdx.x;

    if (blockIdx.x < HA_BLOCKS) {
        // ---------------- scatter role (r6 exact) ----------------
        if (tid < NBUCK) h[tid] = 0;
        __syncthreads();
        const int bstart = blockIdx.x * HA_EPB;
        int r[16], c[16];
#pragma unroll 16
        for (int k = 0; k < 16; ++k) {
            int e = bstart + tid + k * 1024;
            if (e < N_EDGES) {
                r[k] = row[e];
                c[k] = col[e];
                atomicAdd(&h[c[k] >> 7], 1);
            }
        }
        __syncthreads();
        if (tid < NBUCK) {
            int v = h[tid];
            base[tid] = v ? atomicAdd(&bcnt[tid], v) : 0;
            h[tid] = 0;  // reuse as local cursor
        }
        __syncthreads();
#pragma unroll 16
        for (int k = 0; k < 16; ++k) {
            int e = bstart + tid + k * 1024;
            if (e < N_EDGES) {
                int bk = c[k] >> 7;
                int pos = base[bk] + atomicAdd(&h[bk], 1);
                if (pos < CAP) pairs[bk * CAP + pos] = (r[k] << 7) | (c[k] & 127);
            }
        }
    } else {
        // ---------------- gemm role ----------------
        const int w = tid >> 6;
        const int lane = tid & 63;
        const int r16 = lane & 15;   // node within 16-row tile
        const int kb = lane >> 4;    // k-block / feature sub-block
        const int nbase = (blockIdx.x - HA_BLOCKS) * 256 + w * 16;

        // W fragments: direct 16B bf16 loads (8KB table, cache-resident)
        bf16x8 wb[4][2];
#pragma unroll
        for (int t = 0; t < 4; ++t) {
#pragma unroll
            for (int hh = 0; hh < 2; ++hh) {
                wb[t][hh] = *(const bf16x8*)&Wbf[(r16 + 16 * t) * DIM + 32 * hh + kb * 8];
            }
        }

        int arow = nbase + r16;
        if (arow >= N_NODES) arow = N_NODES - 1;
        bf16x8 af[2];
#pragma unroll
        for (int hh = 0; hh < 2; ++hh) {
            const float* xp = &x[(size_t)arow * DIM + 32 * hh + kb * 8];
            float4 p0 = *(const float4*)xp;
            float4 p1 = *(const float4*)(xp + 4);
            bf16x8 f;
            f[0] = f2bf(p0.x); f[1] = f2bf(p0.y); f[2] = f2bf(p0.z); f[3] = f2bf(p0.w);
            f[4] = f2bf(p1.x); f[5] = f2bf(p1.y); f[6] = f2bf(p1.z); f[7] = f2bf(p1.w);
            af[hh] = f;
        }

        const int node = nbase + r16;
        const bool valid = node < N_NODES;
#pragma unroll
        for (int t = 0; t < 4; ++t) {
            // SWAPPED operands: D[row=j, col=node] -> lane (l&15)=node owns
            // 4 consecutive feature cols j = t*16 + kb*4 + i
            f32x4 c = {0.0f, 0.0f, 0.0f, 0.0f};
            c = __builtin_amdgcn_mfma_f32_16x16x32_bf16(wb[t][0], af[0], c, 0, 0, 0);
            c = __builtin_amdgcn_mfma_f32_16x16x32_bf16(wb[t][1], af[1], c, 0, 0, 0);
            if (valid) {
                uint2 ov;
                ov.x = pack2bf(c[0], c[1]);
                ov.y = pack2bf(c[2], c[3]);
                *(uint2*)&sbw[(size_t)node * 32 + t * 8 + kb * 2] = ov;
            }
        }
    }
}

// ---------------------------------------------------------------------------
// 2) per-bucket in-place sort: LDS staging, shfl wave-scan,
//    emits packed CSR metadata info[n] = (start<<8)|deg and dinv[n].
// ---------------------------------------------------------------------------
__global__ __launch_bounds__(256) void sort_kernel(const int* __restrict__ bcnt,
                                                   int* __restrict__ pairs,
                                                   int* __restrict__ info,
                                                   float* __restrict__ dinv) {
    __shared__ int cnt[BK_NODES];
    __shared__ int sc[BK_NODES];
    __shared__ int cur[BK_NODES];
    __shared__ int buf[CAP];
    const int b = blockIdx.x;
    const int tid = threadIdx.x;
    int n = bcnt[b];
    if (n > CAP) n = CAP;
    if (tid < BK_NODES) cnt[tid] = 0;
    __syncthreads();
    for (int p = tid; p < n; p += 256) {
        int pk = pairs[b * CAP + p];
        buf[p] = pk;
        atomicAdd(&cnt[pk & 127], 1);
    }
    __syncthreads();
    // inclusive scan of cnt[0..127]: per-wave shfl scan + cross-wave fixup
    if (tid < BK_NODES) {
        int lane = tid & 63;
        int sum = cnt[tid];
#pragma unroll
        for (int d = 1; d < 64; d <<= 1) {
            int t = __shfl_up(sum, d);
            if (lane >= d) sum += t;
        }
        sc[tid] = sum;
    }
    __syncthreads();
    if (tid >= 64 && tid < BK_NODES) sc[tid] += sc[63];
    __syncthreads();
    if (tid < BK_NODES) {
        int ex = sc[tid] - cnt[tid];  // exclusive
        cur[tid] = ex;
        int node = b * BK_NODES + tid;
        if (node < N_NODES) {
            info[node] = ((b * CAP + ex) << 8) | cnt[tid];
            dinv[node] = rsqrtf((float)(cnt[tid] + 1));  // +1 self-loop
        }
    }
    __syncthreads();
    for (int p = tid; p < n; p += 256) {
        int pk = buf[p];
        int pos = atomicAdd(&cur[pk & 127], 1);
        pairs[b * CAP + pos] = pk >> 7;  // sorted source row index
    }
}

// ---------------------------------------------------------------------------
// 3) aggregate + finalize (r5 8-deep loop shape + per-edge dinv[r]):
//    one node per wave, uint2 x 16 lanes per 128B row, 4 quadrants,
//    unroll 2 -> 8 gathers in flight; dinv loads are L2-resident broadcast.
// ---------------------------------------------------------------------------
__global__ __launch_bounds__(256) void agg_kernel(const int* __restrict__ info,
                                                  const int* __restrict__ srow,
                                                  const uint2* __restrict__ s4,
                                                  const float* __restrict__ dinv,
                                                  const float* __restrict__ bias,
                                                  float* __restrict__ out) {
    int n = __builtin_amdgcn_readfirstlane(blockIdx.x * 4 + (threadIdx.x >> 6));
    if (n >= N_NODES) return;
    const int lane = threadIdx.x & 63;
    const int q = lane >> 4;   // quadrant 0..3: which edge in the group of 4
    const int l = lane & 15;   // 16 lanes x 8B cover one 128B row

    const int iv = info[n];
    const int start = iv >> 8;
    const int end = start + (iv & 255);

    float a0 = 0.0f, a1 = 0.0f, a2 = 0.0f, a3 = 0.0f;
    int p = start + q;
    for (; p + 4 < end; p += 8) {
        int r0 = srow[p];
        int r1 = srow[p + 4];
        float d0 = dinv[r0];
        float d1 = dinv[r1];
        uint2 u0 = s4[(size_t)r0 * 16 + l];
        uint2 u1 = s4[(size_t)r1 * 16 + l];
        a0 = fmaf(d0, bflo(u0.x), a0); a1 = fmaf(d0, bfhi(u0.x), a1);
        a2 = fmaf(d0, bflo(u0.y), a2); a3 = fmaf(d0, bfhi(u0.y), a3);
        a0 = fmaf(d1, bflo(u1.x), a0); a1 = fmaf(d1, bfhi(u1.x), a1);
        a2 = fmaf(d1, bflo(u1.y), a2); a3 = fmaf(d1, bfhi(u1.y), a3);
    }
    if (p < end) {
        int r0 = srow[p];
        float d0 = dinv[r0];
        uint2 u0 = s4[(size_t)r0 * 16 + l];
        a0 = fmaf(d0, bflo(u0.x), a0); a1 = fmaf(d0, bfhi(u0.x), a1);
        a2 = fmaf(d0, bflo(u0.y), a2); a3 = fmaf(d0, bfhi(u0.y), a3);
    }

    // merge quadrants: lanes 0-15 end up with the full sums
    a0 += __shfl_xor(a0, 16); a1 += __shfl_xor(a1, 16);
    a2 += __shfl_xor(a2, 16); a3 += __shfl_xor(a3, 16);
    a0 += __shfl_xor(a0, 32); a1 += __shfl_xor(a1, 32);
    a2 += __shfl_xor(a2, 32); a3 += __shfl_xor(a3, 32);

    if (lane < 16) {
        float dc = dinv[n];
        uint2 us = s4[(size_t)n * 16 + l];  // self-loop term (unscaled sb)
        a0 = fmaf(dc, bflo(us.x), a0); a1 = fmaf(dc, bfhi(us.x), a1);
        a2 = fmaf(dc, bflo(us.y), a2); a3 = fmaf(dc, bfhi(us.y), a3);
        float4 bb = *(const float4*)&bias[4 * l];
        f32x4 o;
        o[0] = fmaxf(fmaf(dc, a0, bb.x), 0.0f);
        o[1] = fmaxf(fmaf(dc, a1, bb.y), 0.0f);
        o[2] = fmaxf(fmaf(dc, a2, bb.z), 0.0f);
        o[3] = fmaxf(fmaf(dc, a3, bb.w), 0.0f);
        // non-temporal: out is write-once, keep it out of L2
        __builtin_nontemporal_store(o, (f32x4*)&out[(size_t)n * DIM + 4 * l]);
    }
}

extern "C" void kernel_launch(void* const* d_in, const int* in_sizes, int n_in,
                              void* d_out, int out_size, void* d_ws, size_t ws_size,
                              hipStream_t stream) {
    const float* x    = (const float*)d_in[0];
    const int*   ei   = (const int*)d_in[1];  // [2, E] int32
    const float* W    = (const float*)d_in[2];
    const float* bias = (const float*)d_in[3];
    float*       out  = (float*)d_out;

    const int* row = ei;            // source nodes
    const int* col = ei + N_EDGES;  // target nodes

    // workspace layout (bytes, 128-aligned):
    //   bcnt  int[1024]              @ 0         (4096)
    //   Wbf   ushort[4096]           @ 4096      (8192)
    //   info  int[100000]            @ 12288     (400000)
    //   dinv  float[100000]          @ 412288    (400000)
    //   pairs int[NBUCK*CAP=2001920] @ 812288    (8007680)  (reused as srow)
    //   sb    bf16[6400000]          @ 8819968   (12800000) -> end ~21.6 MB
    char* ws = (char*)d_ws;
    int*            bcnt  = (int*)(ws + 0);
    unsigned short* Wbf   = (unsigned short*)(ws + 4096);
    int*            info  = (int*)(ws + 12288);
    float*          dinv  = (float*)(ws + 412288);
    int*            pairs = (int*)(ws + 812288);
    uint32*         sbw   = (uint32*)(ws + 8819968);

    init_kernel<<<4, 1024, 0, stream>>>(W, Wbf, bcnt);
    scattergemm_kernel<<<HA_BLOCKS + GEMM_BLOCKS, 1024, 0, stream>>>(
        row, col, bcnt, pairs, x, Wbf, sbw);
    sort_kernel<<<NBUCK, 256, 0, stream>>>(bcnt, pairs, info, dinv);
    agg_kernel<<<(N_NODES + 3) / 4, 256, 0, stream>>>(info, pairs, (const uint2*)sbw,
                                                      dinv, bias, out);
}